// Round 8
// baseline (480.660 us; speedup 1.0000x reference)
//
#include <hip/hip_runtime.h>
#include <hip/hip_fp16.h>

#define NN 50000
#define NE 1600000
#define NC 48
#define NS 10
#define PAD 88          // padded in-degree slots per node; P(deg>88) ~ 1e-10
#define PADN 50176

#define NBUCK 392       // coarse buckets: id>>7 (128 nodes each), ids<50000 -> buckets 0..390
#define NB2   784       // col buckets [0,392) + row buckets [392,784)
#define CAP   4608      // per-bucket record capacity: mean 4096, sd 64, +8 sigma
#define EPB   2048      // edges per bin block (1024 threads x 2)
#define EPT   2

typedef __attribute__((ext_vector_type(8))) _Float16 half8;

// ---- setup pass 1: dual block counting-sort (by col for gather lists, by row for deg) ----
__global__ __launch_bounds__(1024) void bin_kernel(const int* __restrict__ row,
        const int* __restrict__ col, const float* __restrict__ attr,
        int* __restrict__ bcur, uint2* __restrict__ bin, unsigned int* __restrict__ rbin) {
    __shared__ int hcnt[NB2];
    __shared__ int hbase[NB2];
    __shared__ int lofs[NB2];
    __shared__ int sc[1024];
    __shared__ uint2 stageC[EPB];          // 16 KB, col-sorted records
    __shared__ unsigned int stageR[EPB];   // 8 KB, row-sorted records
    int tid = threadIdx.x;
    if (tid < NB2) hcnt[tid] = 0;
    __syncthreads();
    int base = blockIdx.x * EPB;
    int ntot = min(EPB, NE - base);
    unsigned int rec[EPT];
    int cv[EPT];
    #pragma unroll
    for (int k = 0; k < EPT; ++k) {
        int e = base + k * 1024 + tid;
        if (e < NE) {
            int r = row[e], c = col[e];
            unsigned int iq = (unsigned int)rintf(attr[e] * 65535.0f);
            rec[k] = (iq << 16) | (unsigned int)r;   // r < 50000 < 2^16
            cv[k] = c;
            atomicAdd(&hcnt[c >> 7], 1);             // col histogram
            atomicAdd(&hcnt[NBUCK + (r >> 7)], 1);   // row histogram
        } else {
            cv[k] = -1;
        }
    }
    __syncthreads();
    // global chunk reservation for both streams (latency overlaps the scan)
    if (tid < NB2) hbase[tid] = atomicAdd(&bcur[tid], hcnt[tid]);
    sc[tid] = (tid < NB2) ? hcnt[tid] : 0;
    __syncthreads();
    // Hillis-Steele inclusive scan over 1024 slots (all threads participate)
    for (int off = 1; off < 1024; off <<= 1) {
        int t = (tid >= off) ? sc[tid - off] : 0;
        __syncthreads();
        sc[tid] += t;
        __syncthreads();
    }
    if (tid < NB2) {
        lofs[tid] = sc[tid] - hcnt[tid];   // exclusive offset (combined coords)
        hcnt[tid] = 0;                     // reuse as rank counter
    }
    __syncthreads();
    // place into LDS staging, bucket-sorted; col stream occupies [0,ntot),
    // row stream combined coords [ntot,2*ntot) -> stageR index = pos - ntot
    #pragma unroll
    for (int k = 0; k < EPT; ++k) {
        if (cv[k] >= 0) {
            int b = cv[k] >> 7;
            int rk = atomicAdd(&hcnt[b], 1);
            stageC[lofs[b] + rk] = make_uint2(rec[k], (unsigned int)cv[k]);
            int b2 = NBUCK + ((rec[k] & 0xffffu) >> 7);
            int rk2 = atomicAdd(&hcnt[b2], 1);
            stageR[lofs[b2] + rk2 - ntot] = rec[k];
        }
    }
    __syncthreads();
    // stream both stagings -> global, lane-contiguous within each bucket chunk
    for (int i = tid; i < ntot; i += 1024) {
        uint2 rc = stageC[i];
        int b = (int)(rc.y >> 7);
        bin[(size_t)b * CAP + hbase[b] + (i - lofs[b])] = rc;
    }
    for (int i = tid; i < ntot; i += 1024) {
        unsigned int rr = stageR[i];
        int b2 = NBUCK + ((rr & 0xffffu) >> 7);
        rbin[(size_t)(b2 - NBUCK) * CAP + hbase[b2] + (i + ntot - lofs[b2])] = rr;
    }
}

// ---- deg + rdeg + tq in one pass, LDS-only accumulation ----
__global__ __launch_bounds__(1024) void degrdeg_kernel(const int* __restrict__ bcur,
        const unsigned int* __restrict__ rbin, const int* __restrict__ target,
        float* __restrict__ rdeg, int2* __restrict__ tq) {
    __shared__ unsigned int acc[128];
    int rb = blockIdx.x;
    if (threadIdx.x < 128) acc[threadIdx.x] = 0;
    __syncthreads();
    int n = bcur[NBUCK + rb];
    const unsigned int* rp = rbin + (size_t)rb * CAP;
    for (int i = threadIdx.x; i < n; i += 1024) {
        unsigned int rr = rp[i];
        atomicAdd(&acc[rr & 127], rr >> 16);   // LDS atomic, 128-way spread
    }
    __syncthreads();
    if (threadIdx.x < 128) {
        int v = (rb << 7) + threadIdx.x;
        if (v < NN) {
            float rd = 65535.0f / fmaxf((float)acc[threadIdx.x], 1.0f);
            rdeg[v] = rd;
            tq[v] = make_int2(target[v], __float_as_int(rd));
        }
    }
}

// ---- setup pass 2: per-bucket placement into per-col lists ----
__global__ __launch_bounds__(1024) void place_kernel(const int* __restrict__ bcur,
        const uint2* __restrict__ bin, unsigned int* __restrict__ edges,
        int* __restrict__ cnt) {
    __shared__ int ccnt[128];
    int b = blockIdx.x;
    if (threadIdx.x < 128) ccnt[threadIdx.x] = 0;
    __syncthreads();
    int n = bcur[b];
    const uint2* rp = bin + (size_t)b * CAP;
    for (int i = threadIdx.x; i < n; i += 1024) {
        uint2 r = rp[i];
        int c = (int)r.y;
        int pos = atomicAdd(&ccnt[c & 127], 1);
        edges[(size_t)c * PAD + pos] = r.x;
    }
    __syncthreads();
    if (threadIdx.x < 128) {
        int c = (b << 7) + threadIdx.x;
        if (c < NN) cnt[c] = ccnt[threadIdx.x];
    }
}

// ---- step 1 specialized from one-hot: per edge read tq[src] (8B, L2-hot) ----
// R7 -> R8: perm + nontemporal REVERTED (A/B showed +83us: scattering out/p writes
// and edge reads cost more than the ~1.4x loop-divergence it fixed; nt defeated
// L2/L3 retention of the 9x-reread edge array). NEW: q=3 (16 classes/thread) —
// halves gather+edge instructions and edge-record traffic; waves/CU 18 -> 9.
// Discriminates the step bottleneck: instr-bound => -10us/step; request-bound =>
// flat; latency-bound => regress (then next round: q=6 + deeper unroll instead).
__global__ __launch_bounds__(256) void step1_kernel(const int* __restrict__ cnt,
        const unsigned int* __restrict__ edges, const int2* __restrict__ tq,
        const float* __restrict__ rdeg, const float* __restrict__ weight,
        _Float16* __restrict__ p_new, float* __restrict__ out) {
    int idx = blockIdx.x * blockDim.x + threadIdx.x;
    if (idx >= NN * 3) return;
    int v = idx / 3;
    int q = idx - v * 3;
    int n = cnt[v];
    const unsigned int* ep = edges + (size_t)v * PAD;
    int c0 = 16 * q;
    float a[16];
    #pragma unroll
    for (int j = 0; j < 16; ++j) a[j] = 0.f;
    int i = 0;
    for (; i + 4 <= n; i += 4) {
        uint4 pa = *reinterpret_cast<const uint4*>(ep + i);
        int2 t0 = tq[pa.x & 0xffffu];
        int2 t1 = tq[pa.y & 0xffffu];
        int2 t2 = tq[pa.z & 0xffffu];
        int2 t3 = tq[pa.w & 0xffffu];
        float w0 = (float)(pa.x >> 16) * __int_as_float(t0.y);
        float w1 = (float)(pa.y >> 16) * __int_as_float(t1.y);
        float w2 = (float)(pa.z >> 16) * __int_as_float(t2.y);
        float w3 = (float)(pa.w >> 16) * __int_as_float(t3.y);
        int b0 = t0.x - c0, b1 = t1.x - c0, b2 = t2.x - c0, b3 = t3.x - c0;
        #pragma unroll
        for (int j = 0; j < 16; ++j) {
            a[j] += (b0 == j) ? w0 : 0.f;
            a[j] += (b1 == j) ? w1 : 0.f;
            a[j] += (b2 == j) ? w2 : 0.f;
            a[j] += (b3 == j) ? w3 : 0.f;
        }
    }
    for (; i < n; ++i) {
        unsigned int w_ = ep[i];
        int2 t0 = tq[w_ & 0xffffu];
        float w0 = (float)(w_ >> 16) * __int_as_float(t0.y);
        int b0 = t0.x - c0;
        #pragma unroll
        for (int j = 0; j < 16; ++j) a[j] += (b0 == j) ? w0 : 0.f;
    }
    #pragma unroll
    for (int j = 0; j < 16; ++j) a[j] *= (1.0f / 65535.0f);

    size_t off = (size_t)v * NC + c0;
    float w[16];
    #pragma unroll
    for (int j = 0; j < 16; ++j) w[j] = weight[(c0 + j) * NS + 0];
    #pragma unroll
    for (int g = 0; g < 4; ++g)
        *reinterpret_cast<float4*>(out + off + 4 * g) =
            make_float4(a[4*g] * w[4*g], a[4*g+1] * w[4*g+1],
                        a[4*g+2] * w[4*g+2], a[4*g+3] * w[4*g+3]);
    float rd = rdeg[v];
    half8 ph0, ph1;
    #pragma unroll
    for (int j = 0; j < 8; ++j) { ph0[j] = (_Float16)(a[j] * rd); ph1[j] = (_Float16)(a[j+8] * rd); }
    *reinterpret_cast<half8*>(p_new + off) = ph0;
    *reinterpret_cast<half8*>(p_new + off + 8) = ph1;
}

// ---- gather SpMM on premultiplied fp16 state s = h/deg ----
// 32B contiguous gather per edge-thread (2 adjacent half8 from the same p-row).
__device__ __forceinline__ void acc_edge32(unsigned int w_, const char* pb, float* a) {
    const char* src = pb + (w_ & 0xffffu) * (NC * 2);
    const half8 g0 = *reinterpret_cast<const half8*>(src);
    const half8 g1 = *reinterpret_cast<const half8*>(src + 16);
    float wv = (float)(w_ >> 16) * (1.0f / 65535.0f);
    #pragma unroll
    for (int j = 0; j < 8; ++j) a[j] += wv * (float)g0[j];
    #pragma unroll
    for (int j = 0; j < 8; ++j) a[j + 8] += wv * (float)g1[j];
}

// thread (v,q): a = sum_i attr_i * s[src_i, 16q:16q+16]  ( = h_t[v, classes] )
//   out += a * weight[classes, t-1];  if !LAST: s_new[v] = fp16(a * rdeg[v])
template <bool LAST>
__global__ __launch_bounds__(256) void gather_kernel(const int* __restrict__ cnt,
        const unsigned int* __restrict__ edges, const float* __restrict__ rdeg,
        const _Float16* __restrict__ p, _Float16* __restrict__ p_new,
        const float* __restrict__ weight, int t, float* __restrict__ out) {
    int idx = blockIdx.x * blockDim.x + threadIdx.x;
    if (idx >= NN * 3) return;
    int v = idx / 3;
    int q = idx - v * 3;
    int n = cnt[v];
    const unsigned int* ep = edges + (size_t)v * PAD;
    const char* pb = (const char*)p + q * 32;
    float a[16];
    #pragma unroll
    for (int j = 0; j < 16; ++j) a[j] = 0.f;
    int i = 0;
    for (; i + 4 <= n; i += 4) {
        uint4 pa = *reinterpret_cast<const uint4*>(ep + i);
        acc_edge32(pa.x, pb, a); acc_edge32(pa.y, pb, a);
        acc_edge32(pa.z, pb, a); acc_edge32(pa.w, pb, a);
    }
    for (; i < n; ++i) acc_edge32(ep[i], pb, a);

    size_t off = (size_t)v * NC + q * 16;
    int c0 = 16 * q;
    float w[16];
    #pragma unroll
    for (int j = 0; j < 16; ++j) w[j] = weight[(c0 + j) * NS + (t - 1)];
    float* op = out + off;
    #pragma unroll
    for (int g = 0; g < 4; ++g) {
        float4 o = *reinterpret_cast<float4*>(op + 4 * g);
        o.x += a[4*g] * w[4*g];   o.y += a[4*g+1] * w[4*g+1];
        o.z += a[4*g+2] * w[4*g+2]; o.w += a[4*g+3] * w[4*g+3];
        *reinterpret_cast<float4*>(op + 4 * g) = o;
    }
    if (!LAST) {
        float rd = rdeg[v];
        half8 ph0, ph1;
        #pragma unroll
        for (int j = 0; j < 8; ++j) { ph0[j] = (_Float16)(a[j] * rd); ph1[j] = (_Float16)(a[j+8] * rd); }
        *reinterpret_cast<half8*>(p_new + off) = ph0;
        *reinterpret_cast<half8*>(p_new + off + 8) = ph1;
    }
}

extern "C" void kernel_launch(void* const* d_in, const int* in_sizes, int n_in,
                              void* d_out, int out_size, void* d_ws, size_t ws_size,
                              hipStream_t stream) {
    const int*   edge_index = (const int*)d_in[0];      // [2, E]: row then col
    const float* edge_attr  = (const float*)d_in[1];    // [E]
    const int*   target     = (const int*)d_in[2];      // [N]
    const float* weight     = (const float*)d_in[3];    // [C, S]
    float* out = (float*)d_out;                         // [N, C]

    const int* row = edge_index;
    const int* col = edge_index + NE;

    // ws layout (dwords):
    //   rdeg[PADN] | bcur[1024] | cnt[PADN] | tq[NN] int2 | edges[NN*PAD] | bin[NBUCK*CAP] uint2
    // aliases (sequential lifetimes): rbin = edges region (bin writes, degrdeg reads,
    // then place overwrites); pA|pB = tail 9.6 MB of bin (dead after place).
    float*        rdeg  = (float*)d_ws;
    int*          bcur  = (int*)(rdeg + PADN);
    int*          cnt   = bcur + 1024;
    int2*         tq    = (int2*)(cnt + PADN);
    unsigned int* edges = (unsigned int*)(tq + NN);
    unsigned int* rbin  = edges;
    uint2*        bin   = (uint2*)(edges + (size_t)NN * PAD);
    _Float16*     pA    = (_Float16*)((char*)bin + (size_t)NBUCK * CAP * sizeof(uint2)
                                      - (size_t)2 * NN * NC * sizeof(_Float16));
    _Float16*     pB    = pA + (size_t)NN * NC;

    hipMemsetAsync(bcur, 0, 1024 * sizeof(int), stream);  // bucket cursors only

    bin_kernel<<<(NE + EPB - 1) / EPB, 1024, 0, stream>>>(row, col, edge_attr,
            bcur, bin, rbin);
    degrdeg_kernel<<<NBUCK, 1024, 0, stream>>>(bcur, rbin, target, rdeg, tq);
    place_kernel<<<NBUCK, 1024, 0, stream>>>(bcur, bin, edges, cnt);

    const int gblocks = (NN * 3 + 255) / 256;
    _Float16* p = pA;
    _Float16* p_new = pB;
    step1_kernel<<<gblocks, 256, 0, stream>>>(cnt, edges, tq, rdeg, weight, p, out);
    for (int t = 2; t <= NS - 1; ++t) {
        gather_kernel<false><<<gblocks, 256, 0, stream>>>(cnt, edges, rdeg, p, p_new,
                                                          weight, t, out);
        _Float16* tmp = p; p = p_new; p_new = tmp;
    }
    gather_kernel<true><<<gblocks, 256, 0, stream>>>(cnt, edges, rdeg, p, p_new,
                                                     weight, NS, out);
}

// Round 9
// 409.208 us; speedup vs baseline: 1.1746x; 1.1746x over previous
//
#include <hip/hip_runtime.h>
#include <hip/hip_fp16.h>

#define NN 50000
#define NE 1600000
#define NC 48
#define NS 10
#define PAD 88          // padded in-degree slots per node; P(deg>88) ~ 1e-10
#define PADN 50176

#define NBUCK 392       // coarse buckets: id>>7 (128 nodes each), ids<50000 -> buckets 0..390
#define NB2   784       // col buckets [0,392) + row buckets [392,784)
#define CAP   4608      // per-bucket record capacity: mean 4096, sd 64, +8 sigma
#define EPB   2048      // edges per bin block (1024 threads x 2)
#define EPT   2

typedef __attribute__((ext_vector_type(8))) _Float16 half8;

// ---- setup pass 1: dual block counting-sort (by col for gather lists, by row for deg) ----
__global__ __launch_bounds__(1024) void bin_kernel(const int* __restrict__ row,
        const int* __restrict__ col, const float* __restrict__ attr,
        int* __restrict__ bcur, uint2* __restrict__ bin, unsigned int* __restrict__ rbin) {
    __shared__ int hcnt[NB2];
    __shared__ int hbase[NB2];
    __shared__ int lofs[NB2];
    __shared__ int sc[1024];
    __shared__ uint2 stageC[EPB];          // 16 KB, col-sorted records
    __shared__ unsigned int stageR[EPB];   // 8 KB, row-sorted records
    int tid = threadIdx.x;
    if (tid < NB2) hcnt[tid] = 0;
    __syncthreads();
    int base = blockIdx.x * EPB;
    int ntot = min(EPB, NE - base);
    unsigned int rec[EPT];
    int cv[EPT];
    #pragma unroll
    for (int k = 0; k < EPT; ++k) {
        int e = base + k * 1024 + tid;
        if (e < NE) {
            int r = row[e], c = col[e];
            unsigned int iq = (unsigned int)rintf(attr[e] * 65535.0f);
            rec[k] = (iq << 16) | (unsigned int)r;   // r < 50000 < 2^16
            cv[k] = c;
            atomicAdd(&hcnt[c >> 7], 1);             // col histogram
            atomicAdd(&hcnt[NBUCK + (r >> 7)], 1);   // row histogram
        } else {
            cv[k] = -1;
        }
    }
    __syncthreads();
    // global chunk reservation for both streams (latency overlaps the scan)
    if (tid < NB2) hbase[tid] = atomicAdd(&bcur[tid], hcnt[tid]);
    sc[tid] = (tid < NB2) ? hcnt[tid] : 0;
    __syncthreads();
    // Hillis-Steele inclusive scan over 1024 slots (all threads participate)
    for (int off = 1; off < 1024; off <<= 1) {
        int t = (tid >= off) ? sc[tid - off] : 0;
        __syncthreads();
        sc[tid] += t;
        __syncthreads();
    }
    if (tid < NB2) {
        lofs[tid] = sc[tid] - hcnt[tid];   // exclusive offset (combined coords)
        hcnt[tid] = 0;                     // reuse as rank counter
    }
    __syncthreads();
    // place into LDS staging, bucket-sorted; col stream occupies [0,ntot),
    // row stream combined coords [ntot,2*ntot) -> stageR index = pos - ntot
    #pragma unroll
    for (int k = 0; k < EPT; ++k) {
        if (cv[k] >= 0) {
            int b = cv[k] >> 7;
            int rk = atomicAdd(&hcnt[b], 1);
            stageC[lofs[b] + rk] = make_uint2(rec[k], (unsigned int)cv[k]);
            int b2 = NBUCK + ((rec[k] & 0xffffu) >> 7);
            int rk2 = atomicAdd(&hcnt[b2], 1);
            stageR[lofs[b2] + rk2 - ntot] = rec[k];
        }
    }
    __syncthreads();
    // stream both stagings -> global, lane-contiguous within each bucket chunk
    for (int i = tid; i < ntot; i += 1024) {
        uint2 rc = stageC[i];
        int b = (int)(rc.y >> 7);
        bin[(size_t)b * CAP + hbase[b] + (i - lofs[b])] = rc;
    }
    for (int i = tid; i < ntot; i += 1024) {
        unsigned int rr = stageR[i];
        int b2 = NBUCK + ((rr & 0xffffu) >> 7);
        rbin[(size_t)(b2 - NBUCK) * CAP + hbase[b2] + (i + ntot - lofs[b2])] = rr;
    }
}

// ---- deg + rdeg + tq in one pass, LDS-only accumulation ----
__global__ __launch_bounds__(1024) void degrdeg_kernel(const int* __restrict__ bcur,
        const unsigned int* __restrict__ rbin, const int* __restrict__ target,
        float* __restrict__ rdeg, int2* __restrict__ tq) {
    __shared__ unsigned int acc[128];
    int rb = blockIdx.x;
    if (threadIdx.x < 128) acc[threadIdx.x] = 0;
    __syncthreads();
    int n = bcur[NBUCK + rb];
    const unsigned int* rp = rbin + (size_t)rb * CAP;
    for (int i = threadIdx.x; i < n; i += 1024) {
        unsigned int rr = rp[i];
        atomicAdd(&acc[rr & 127], rr >> 16);   // LDS atomic, 128-way spread
    }
    __syncthreads();
    if (threadIdx.x < 128) {
        int v = (rb << 7) + threadIdx.x;
        if (v < NN) {
            float rd = 65535.0f / fmaxf((float)acc[threadIdx.x], 1.0f);
            rdeg[v] = rd;
            tq[v] = make_int2(target[v], __float_as_int(rd));
        }
    }
}

// ---- setup pass 2: per-bucket placement into per-col lists ----
__global__ __launch_bounds__(1024) void place_kernel(const int* __restrict__ bcur,
        const uint2* __restrict__ bin, unsigned int* __restrict__ edges,
        int* __restrict__ cnt) {
    __shared__ int ccnt[128];
    int b = blockIdx.x;
    if (threadIdx.x < 128) ccnt[threadIdx.x] = 0;
    __syncthreads();
    int n = bcur[b];
    const uint2* rp = bin + (size_t)b * CAP;
    for (int i = threadIdx.x; i < n; i += 1024) {
        uint2 r = rp[i];
        int c = (int)r.y;
        int pos = atomicAdd(&ccnt[c & 127], 1);
        edges[(size_t)c * PAD + pos] = r.x;
    }
    __syncthreads();
    if (threadIdx.x < 128) {
        int c = (b << 7) + threadIdx.x;
        if (c < NN) cnt[c] = ccnt[threadIdx.x];
    }
}

// ---- step kernels: R8 -> R9 ----
// q=3 REVERTED (latency-bound confirmed: 2344 waves @15% occ -> 41.5us/step, worse
// than q=6's ~36). Back to q=6 (8 classes/thread) PLUS h-split: each (v,q) is
// handled by 2 threads that sum disjoint halves of the edge chunks, combined with
// one __shfl_xor per accumulator (pair = adjacent lanes). 9375 waves -> occ cap
// 100%. Epilogue splits too: h=0 does out RMW, h=1 writes p_new.
// Numerics: one reassociation per (v,q) sum (halfA + halfB); absmax drift ~1e-5.
__device__ __forceinline__ void hrange(int n, int h, int& lo, int& hi) {
    int mid = 4 * (((n + 3) / 4 + 1) / 2);   // half the uint4 chunks, h=0 gets ceil
    lo = h ? mid : 0;
    hi = h ? n : min(mid, n);
}

// ---- step 1 specialized from one-hot: per edge read tq[src] (8B, L2-hot) ----
__global__ __launch_bounds__(256) void step1_kernel(const int* __restrict__ cnt,
        const unsigned int* __restrict__ edges, const int2* __restrict__ tq,
        const float* __restrict__ rdeg, const float* __restrict__ weight,
        _Float16* __restrict__ p_new, float* __restrict__ out) {
    int idx = blockIdx.x * blockDim.x + threadIdx.x;
    if (idx >= NN * 12) return;
    int v = idx / 12;
    int r12 = idx - v * 12;
    int q = r12 >> 1;
    int h = r12 & 1;
    int n = cnt[v];
    const unsigned int* ep = edges + (size_t)v * PAD;
    int c0 = 8 * q;
    float a[8] = {0.f, 0.f, 0.f, 0.f, 0.f, 0.f, 0.f, 0.f};
    int lo, hi;
    hrange(n, h, lo, hi);
    int i = lo;
    for (; i + 4 <= hi; i += 4) {
        uint4 pa = *reinterpret_cast<const uint4*>(ep + i);
        int2 t0 = tq[pa.x & 0xffffu];
        int2 t1 = tq[pa.y & 0xffffu];
        int2 t2 = tq[pa.z & 0xffffu];
        int2 t3 = tq[pa.w & 0xffffu];
        float w0 = (float)(pa.x >> 16) * __int_as_float(t0.y);
        float w1 = (float)(pa.y >> 16) * __int_as_float(t1.y);
        float w2 = (float)(pa.z >> 16) * __int_as_float(t2.y);
        float w3 = (float)(pa.w >> 16) * __int_as_float(t3.y);
        int b0 = t0.x - c0, b1 = t1.x - c0, b2 = t2.x - c0, b3 = t3.x - c0;
        #pragma unroll
        for (int j = 0; j < 8; ++j) {
            a[j] += (b0 == j) ? w0 : 0.f;
            a[j] += (b1 == j) ? w1 : 0.f;
            a[j] += (b2 == j) ? w2 : 0.f;
            a[j] += (b3 == j) ? w3 : 0.f;
        }
    }
    for (; i < hi; ++i) {
        unsigned int w_ = ep[i];
        int2 t0 = tq[w_ & 0xffffu];
        float w0 = (float)(w_ >> 16) * __int_as_float(t0.y);
        int b0 = t0.x - c0;
        #pragma unroll
        for (int j = 0; j < 8; ++j) a[j] += (b0 == j) ? w0 : 0.f;
    }
    // pair-combine: lanes 2k (h=0) and 2k+1 (h=1) hold the two halves
    #pragma unroll
    for (int j = 0; j < 8; ++j) a[j] += __shfl_xor(a[j], 1);
    #pragma unroll
    for (int j = 0; j < 8; ++j) a[j] *= (1.0f / 65535.0f);

    size_t off = (size_t)v * NC + c0;
    if (h == 0) {
        float w[8];
        #pragma unroll
        for (int j = 0; j < 8; ++j) w[j] = weight[(c0 + j) * NS + 0];
        *reinterpret_cast<float4*>(out + off) =
            make_float4(a[0] * w[0], a[1] * w[1], a[2] * w[2], a[3] * w[3]);
        *reinterpret_cast<float4*>(out + off + 4) =
            make_float4(a[4] * w[4], a[5] * w[5], a[6] * w[6], a[7] * w[7]);
    } else {
        float rd = rdeg[v];
        half8 ph;
        #pragma unroll
        for (int j = 0; j < 8; ++j) ph[j] = (_Float16)(a[j] * rd);
        *reinterpret_cast<half8*>(p_new + off) = ph;
    }
}

// ---- gather SpMM on premultiplied fp16 state s = h/deg ----
__device__ __forceinline__ void acc_edge(unsigned int w_, const char* pb, float* a) {
    const half8 g = *reinterpret_cast<const half8*>(pb + (w_ & 0xffffu) * (NC * 2));
    float wv = (float)(w_ >> 16) * (1.0f / 65535.0f);
    #pragma unroll
    for (int j = 0; j < 8; ++j) a[j] += wv * (float)g[j];
}

// thread (v,q,h): partial a = sum_{i in half h} attr_i * s[src_i, 8q:8q+8]
//   shfl-combine -> h=0: out += a*w;  h=1 (!LAST): s_new[v] = fp16(a * rdeg[v])
template <bool LAST>
__global__ __launch_bounds__(256) void gather_kernel(const int* __restrict__ cnt,
        const unsigned int* __restrict__ edges, const float* __restrict__ rdeg,
        const _Float16* __restrict__ p, _Float16* __restrict__ p_new,
        const float* __restrict__ weight, int t, float* __restrict__ out) {
    int idx = blockIdx.x * blockDim.x + threadIdx.x;
    if (idx >= NN * 12) return;
    int v = idx / 12;
    int r12 = idx - v * 12;
    int q = r12 >> 1;
    int h = r12 & 1;
    int n = cnt[v];
    const unsigned int* ep = edges + (size_t)v * PAD;
    const char* pb = (const char*)p + q * 16;
    float a[8] = {0.f, 0.f, 0.f, 0.f, 0.f, 0.f, 0.f, 0.f};
    int lo, hi;
    hrange(n, h, lo, hi);
    int i = lo;
    for (; i + 4 <= hi; i += 4) {
        uint4 pa = *reinterpret_cast<const uint4*>(ep + i);
        acc_edge(pa.x, pb, a); acc_edge(pa.y, pb, a);
        acc_edge(pa.z, pb, a); acc_edge(pa.w, pb, a);
    }
    for (; i < hi; ++i) acc_edge(ep[i], pb, a);

    // pair-combine across the h-split
    #pragma unroll
    for (int j = 0; j < 8; ++j) a[j] += __shfl_xor(a[j], 1);

    size_t off = (size_t)v * NC + q * 8;
    int c0 = 8 * q;
    if (h == 0) {
        float w[8];
        #pragma unroll
        for (int j = 0; j < 8; ++j) w[j] = weight[(c0 + j) * NS + (t - 1)];
        float* op = out + off;
        float4 o0 = *reinterpret_cast<float4*>(op);
        float4 o1 = *reinterpret_cast<float4*>(op + 4);
        o0.x += a[0] * w[0]; o0.y += a[1] * w[1]; o0.z += a[2] * w[2]; o0.w += a[3] * w[3];
        o1.x += a[4] * w[4]; o1.y += a[5] * w[5]; o1.z += a[6] * w[6]; o1.w += a[7] * w[7];
        *reinterpret_cast<float4*>(op) = o0;
        *reinterpret_cast<float4*>(op + 4) = o1;
    } else if (!LAST) {
        float rd = rdeg[v];
        half8 ph;
        #pragma unroll
        for (int j = 0; j < 8; ++j) ph[j] = (_Float16)(a[j] * rd);
        *reinterpret_cast<half8*>(p_new + off) = ph;
    }
}

extern "C" void kernel_launch(void* const* d_in, const int* in_sizes, int n_in,
                              void* d_out, int out_size, void* d_ws, size_t ws_size,
                              hipStream_t stream) {
    const int*   edge_index = (const int*)d_in[0];      // [2, E]: row then col
    const float* edge_attr  = (const float*)d_in[1];    // [E]
    const int*   target     = (const int*)d_in[2];      // [N]
    const float* weight     = (const float*)d_in[3];    // [C, S]
    float* out = (float*)d_out;                         // [N, C]

    const int* row = edge_index;
    const int* col = edge_index + NE;

    // ws layout (dwords):
    //   rdeg[PADN] | bcur[1024] | cnt[PADN] | tq[NN] int2 | edges[NN*PAD] | bin[NBUCK*CAP] uint2
    // aliases (sequential lifetimes): rbin = edges region (bin writes, degrdeg reads,
    // then place overwrites); pA|pB = tail 9.6 MB of bin (dead after place).
    float*        rdeg  = (float*)d_ws;
    int*          bcur  = (int*)(rdeg + PADN);
    int*          cnt   = bcur + 1024;
    int2*         tq    = (int2*)(cnt + PADN);
    unsigned int* edges = (unsigned int*)(tq + NN);
    unsigned int* rbin  = edges;
    uint2*        bin   = (uint2*)(edges + (size_t)NN * PAD);
    _Float16*     pA    = (_Float16*)((char*)bin + (size_t)NBUCK * CAP * sizeof(uint2)
                                      - (size_t)2 * NN * NC * sizeof(_Float16));
    _Float16*     pB    = pA + (size_t)NN * NC;

    hipMemsetAsync(bcur, 0, 1024 * sizeof(int), stream);  // bucket cursors only

    bin_kernel<<<(NE + EPB - 1) / EPB, 1024, 0, stream>>>(row, col, edge_attr,
            bcur, bin, rbin);
    degrdeg_kernel<<<NBUCK, 1024, 0, stream>>>(bcur, rbin, target, rdeg, tq);
    place_kernel<<<NBUCK, 1024, 0, stream>>>(bcur, bin, edges, cnt);

    const int gblocks = (NN * 12 + 255) / 256;
    _Float16* p = pA;
    _Float16* p_new = pB;
    step1_kernel<<<gblocks, 256, 0, stream>>>(cnt, edges, tq, rdeg, weight, p, out);
    for (int t = 2; t <= NS - 1; ++t) {
        gather_kernel<false><<<gblocks, 256, 0, stream>>>(cnt, edges, rdeg, p, p_new,
                                                          weight, t, out);
        _Float16* tmp = p; p = p_new; p_new = tmp;
    }
    gather_kernel<true><<<gblocks, 256, 0, stream>>>(cnt, edges, rdeg, p, p_new,
                                                     weight, NS, out);
}

// Round 10
// 383.877 us; speedup vs baseline: 1.2521x; 1.0660x over previous
//
#include <hip/hip_runtime.h>
#include <hip/hip_fp16.h>

#define NN 50000
#define NE 1600000
#define NC 48
#define NS 10
#define PAD 88          // padded in-degree slots per node; P(deg>88) ~ 1e-10
#define PADN 50176

#define NBUCK 392       // coarse buckets: id>>7 (128 nodes each), ids<50000 -> buckets 0..390
#define NB2   784       // col buckets [0,392) + row buckets [392,784)
#define CAP   4608      // per-bucket record capacity: mean 4096, sd 64, +8 sigma
#define EPB   2048      // edges per bin block (1024 threads x 2)
#define EPT   2

typedef __attribute__((ext_vector_type(8))) _Float16 half8;

// ---- setup pass 1: dual block counting-sort (by col for gather lists, by row for deg) ----
__global__ __launch_bounds__(1024) void bin_kernel(const int* __restrict__ row,
        const int* __restrict__ col, const float* __restrict__ attr,
        int* __restrict__ bcur, uint2* __restrict__ bin, unsigned int* __restrict__ rbin) {
    __shared__ int hcnt[NB2];
    __shared__ int hbase[NB2];
    __shared__ int lofs[NB2];
    __shared__ int sc[1024];
    __shared__ uint2 stageC[EPB];          // 16 KB, col-sorted records
    __shared__ unsigned int stageR[EPB];   // 8 KB, row-sorted records
    int tid = threadIdx.x;
    if (tid < NB2) hcnt[tid] = 0;
    __syncthreads();
    int base = blockIdx.x * EPB;
    int ntot = min(EPB, NE - base);
    unsigned int rec[EPT];
    int cv[EPT];
    #pragma unroll
    for (int k = 0; k < EPT; ++k) {
        int e = base + k * 1024 + tid;
        if (e < NE) {
            int r = row[e], c = col[e];
            unsigned int iq = (unsigned int)rintf(attr[e] * 65535.0f);
            rec[k] = (iq << 16) | (unsigned int)r;   // r < 50000 < 2^16
            cv[k] = c;
            atomicAdd(&hcnt[c >> 7], 1);             // col histogram
            atomicAdd(&hcnt[NBUCK + (r >> 7)], 1);   // row histogram
        } else {
            cv[k] = -1;
        }
    }
    __syncthreads();
    // global chunk reservation for both streams (latency overlaps the scan)
    if (tid < NB2) hbase[tid] = atomicAdd(&bcur[tid], hcnt[tid]);
    sc[tid] = (tid < NB2) ? hcnt[tid] : 0;
    __syncthreads();
    // Hillis-Steele inclusive scan over 1024 slots (all threads participate)
    for (int off = 1; off < 1024; off <<= 1) {
        int t = (tid >= off) ? sc[tid - off] : 0;
        __syncthreads();
        sc[tid] += t;
        __syncthreads();
    }
    if (tid < NB2) {
        lofs[tid] = sc[tid] - hcnt[tid];   // exclusive offset (combined coords)
        hcnt[tid] = 0;                     // reuse as rank counter
    }
    __syncthreads();
    // place into LDS staging, bucket-sorted; col stream occupies [0,ntot),
    // row stream combined coords [ntot,2*ntot) -> stageR index = pos - ntot
    #pragma unroll
    for (int k = 0; k < EPT; ++k) {
        if (cv[k] >= 0) {
            int b = cv[k] >> 7;
            int rk = atomicAdd(&hcnt[b], 1);
            stageC[lofs[b] + rk] = make_uint2(rec[k], (unsigned int)cv[k]);
            int b2 = NBUCK + ((rec[k] & 0xffffu) >> 7);
            int rk2 = atomicAdd(&hcnt[b2], 1);
            stageR[lofs[b2] + rk2 - ntot] = rec[k];
        }
    }
    __syncthreads();
    // stream both stagings -> global, lane-contiguous within each bucket chunk
    for (int i = tid; i < ntot; i += 1024) {
        uint2 rc = stageC[i];
        int b = (int)(rc.y >> 7);
        bin[(size_t)b * CAP + hbase[b] + (i - lofs[b])] = rc;
    }
    for (int i = tid; i < ntot; i += 1024) {
        unsigned int rr = stageR[i];
        int b2 = NBUCK + ((rr & 0xffffu) >> 7);
        rbin[(size_t)(b2 - NBUCK) * CAP + hbase[b2] + (i + ntot - lofs[b2])] = rr;
    }
}

// ---- deg + rdeg + tq in one pass, LDS-only accumulation ----
__global__ __launch_bounds__(1024) void degrdeg_kernel(const int* __restrict__ bcur,
        const unsigned int* __restrict__ rbin, const int* __restrict__ target,
        float* __restrict__ rdeg, int2* __restrict__ tq) {
    __shared__ unsigned int acc[128];
    int rb = blockIdx.x;
    if (threadIdx.x < 128) acc[threadIdx.x] = 0;
    __syncthreads();
    int n = bcur[NBUCK + rb];
    const unsigned int* rp = rbin + (size_t)rb * CAP;
    for (int i = threadIdx.x; i < n; i += 1024) {
        unsigned int rr = rp[i];
        atomicAdd(&acc[rr & 127], rr >> 16);   // LDS atomic, 128-way spread
    }
    __syncthreads();
    if (threadIdx.x < 128) {
        int v = (rb << 7) + threadIdx.x;
        if (v < NN) {
            float rd = 65535.0f / fmaxf((float)acc[threadIdx.x], 1.0f);
            rdeg[v] = rd;
            tq[v] = make_int2(target[v], __float_as_int(rd));
        }
    }
}

// ---- setup pass 2: per-bucket placement into per-col lists ----
__global__ __launch_bounds__(1024) void place_kernel(const int* __restrict__ bcur,
        const uint2* __restrict__ bin, unsigned int* __restrict__ edges,
        int* __restrict__ cnt) {
    __shared__ int ccnt[128];
    int b = blockIdx.x;
    if (threadIdx.x < 128) ccnt[threadIdx.x] = 0;
    __syncthreads();
    int n = bcur[b];
    const uint2* rp = bin + (size_t)b * CAP;
    for (int i = threadIdx.x; i < n; i += 1024) {
        uint2 r = rp[i];
        int c = (int)r.y;
        int pos = atomicAdd(&ccnt[c & 127], 1);
        edges[(size_t)c * PAD + pos] = r.x;
    }
    __syncthreads();
    if (threadIdx.x < 128) {
        int c = (b << 7) + threadIdx.x;
        if (c < NN) cnt[c] = ccnt[threadIdx.x];
    }
}

// ---- step 1 specialized from one-hot: per edge read tq[src] (8B, L2-hot) ----
// R9 -> R10: h-split REVERTED (occupancy ladder 2344/4688/9375 waves ->
// 41.5/36.5/38 us: saturates at 4688, TLP not the limiter). Back to R4's exact
// q=6 structure (bit-identical numerics).
__global__ __launch_bounds__(256) void step1_kernel(const int* __restrict__ cnt,
        const unsigned int* __restrict__ edges, const int2* __restrict__ tq,
        const float* __restrict__ rdeg, const float* __restrict__ weight,
        _Float16* __restrict__ p_new, float* __restrict__ out) {
    int idx = blockIdx.x * blockDim.x + threadIdx.x;
    if (idx >= NN * 6) return;
    int v = idx / 6;
    int q = idx - v * 6;
    int n = cnt[v];
    const unsigned int* ep = edges + (size_t)v * PAD;
    int c0 = 8 * q;
    float a[8] = {0.f, 0.f, 0.f, 0.f, 0.f, 0.f, 0.f, 0.f};
    int i = 0;
    for (; i + 4 <= n; i += 4) {
        uint4 pa = *reinterpret_cast<const uint4*>(ep + i);
        int2 t0 = tq[pa.x & 0xffffu];
        int2 t1 = tq[pa.y & 0xffffu];
        int2 t2 = tq[pa.z & 0xffffu];
        int2 t3 = tq[pa.w & 0xffffu];
        float w0 = (float)(pa.x >> 16) * __int_as_float(t0.y);
        float w1 = (float)(pa.y >> 16) * __int_as_float(t1.y);
        float w2 = (float)(pa.z >> 16) * __int_as_float(t2.y);
        float w3 = (float)(pa.w >> 16) * __int_as_float(t3.y);
        int b0 = t0.x - c0, b1 = t1.x - c0, b2 = t2.x - c0, b3 = t3.x - c0;
        #pragma unroll
        for (int j = 0; j < 8; ++j) {
            a[j] += (b0 == j) ? w0 : 0.f;
            a[j] += (b1 == j) ? w1 : 0.f;
            a[j] += (b2 == j) ? w2 : 0.f;
            a[j] += (b3 == j) ? w3 : 0.f;
        }
    }
    for (; i < n; ++i) {
        unsigned int w_ = ep[i];
        int2 t0 = tq[w_ & 0xffffu];
        float w0 = (float)(w_ >> 16) * __int_as_float(t0.y);
        int b0 = t0.x - c0;
        #pragma unroll
        for (int j = 0; j < 8; ++j) a[j] += (b0 == j) ? w0 : 0.f;
    }
    #pragma unroll
    for (int j = 0; j < 8; ++j) a[j] *= (1.0f / 65535.0f);

    size_t off = (size_t)v * NC + c0;
    float w[8];
    #pragma unroll
    for (int j = 0; j < 8; ++j) w[j] = weight[(c0 + j) * NS + 0];
    *reinterpret_cast<float4*>(out + off) =
        make_float4(a[0] * w[0], a[1] * w[1], a[2] * w[2], a[3] * w[3]);
    *reinterpret_cast<float4*>(out + off + 4) =
        make_float4(a[4] * w[4], a[5] * w[5], a[6] * w[6], a[7] * w[7]);
    float rd = rdeg[v];
    half8 ph;
    #pragma unroll
    for (int j = 0; j < 8; ++j) ph[j] = (_Float16)(a[j] * rd);
    *reinterpret_cast<half8*>(p_new + off) = ph;
}

// ---- gather SpMM on premultiplied fp16 state s = h/deg ----
// R10 NEW: 8-deep explicit load batching. The old acc_edge did load->use per edge
// (1 outstanding gather per wave; VALUBusy 12%; ~400-cy L2 latency exposed per
// edge). Now all 8 p-row gathers of an unrolled block are issued into registers
// BEFORE any convert/fma -> 8 in flight per wave. Edge fma order unchanged
// (edge i fully accumulated before i+1) -> bit-identical results.
__device__ __forceinline__ const half8* prow(unsigned int w_, const char* pb) {
    return reinterpret_cast<const half8*>(pb + (w_ & 0xffffu) * (NC * 2));
}

__device__ __forceinline__ void fma8(float* a, float wv, half8 g) {
    #pragma unroll
    for (int j = 0; j < 8; ++j) a[j] += wv * (float)g[j];
}

template <bool LAST>
__global__ __launch_bounds__(256) void gather_kernel(const int* __restrict__ cnt,
        const unsigned int* __restrict__ edges, const float* __restrict__ rdeg,
        const _Float16* __restrict__ p, _Float16* __restrict__ p_new,
        const float* __restrict__ weight, int t, float* __restrict__ out) {
    int idx = blockIdx.x * blockDim.x + threadIdx.x;
    if (idx >= NN * 6) return;
    int v = idx / 6;
    int q = idx - v * 6;
    int n = cnt[v];
    const unsigned int* ep = edges + (size_t)v * PAD;
    const char* pb = (const char*)p + q * 16;
    float a[8] = {0.f, 0.f, 0.f, 0.f, 0.f, 0.f, 0.f, 0.f};
    int i = 0;
    for (; i + 8 <= n; i += 8) {
        uint4 pa = *reinterpret_cast<const uint4*>(ep + i);
        uint4 pc = *reinterpret_cast<const uint4*>(ep + i + 4);
        // issue all 8 gathers before any use (8 loads in flight per wave)
        half8 g0 = *prow(pa.x, pb);
        half8 g1 = *prow(pa.y, pb);
        half8 g2 = *prow(pa.z, pb);
        half8 g3 = *prow(pa.w, pb);
        half8 g4 = *prow(pc.x, pb);
        half8 g5 = *prow(pc.y, pb);
        half8 g6 = *prow(pc.z, pb);
        half8 g7 = *prow(pc.w, pb);
        const float sc = 1.0f / 65535.0f;
        fma8(a, (float)(pa.x >> 16) * sc, g0);
        fma8(a, (float)(pa.y >> 16) * sc, g1);
        fma8(a, (float)(pa.z >> 16) * sc, g2);
        fma8(a, (float)(pa.w >> 16) * sc, g3);
        fma8(a, (float)(pc.x >> 16) * sc, g4);
        fma8(a, (float)(pc.y >> 16) * sc, g5);
        fma8(a, (float)(pc.z >> 16) * sc, g6);
        fma8(a, (float)(pc.w >> 16) * sc, g7);
    }
    if (i + 4 <= n) {
        uint4 pa = *reinterpret_cast<const uint4*>(ep + i);
        half8 g0 = *prow(pa.x, pb);
        half8 g1 = *prow(pa.y, pb);
        half8 g2 = *prow(pa.z, pb);
        half8 g3 = *prow(pa.w, pb);
        const float sc = 1.0f / 65535.0f;
        fma8(a, (float)(pa.x >> 16) * sc, g0);
        fma8(a, (float)(pa.y >> 16) * sc, g1);
        fma8(a, (float)(pa.z >> 16) * sc, g2);
        fma8(a, (float)(pa.w >> 16) * sc, g3);
        i += 4;
    }
    for (; i < n; ++i) {
        unsigned int w_ = ep[i];
        fma8(a, (float)(w_ >> 16) * (1.0f / 65535.0f), *prow(w_, pb));
    }

    size_t off = (size_t)v * NC + q * 8;
    int c0 = 8 * q;
    float w[8];
    #pragma unroll
    for (int j = 0; j < 8; ++j) w[j] = weight[(c0 + j) * NS + (t - 1)];
    float* op = out + off;
    float4 o0 = *reinterpret_cast<float4*>(op);
    float4 o1 = *reinterpret_cast<float4*>(op + 4);
    o0.x += a[0] * w[0]; o0.y += a[1] * w[1]; o0.z += a[2] * w[2]; o0.w += a[3] * w[3];
    o1.x += a[4] * w[4]; o1.y += a[5] * w[5]; o1.z += a[6] * w[6]; o1.w += a[7] * w[7];
    *reinterpret_cast<float4*>(op) = o0;
    *reinterpret_cast<float4*>(op + 4) = o1;
    if (!LAST) {
        float rd = rdeg[v];
        half8 ph;
        #pragma unroll
        for (int j = 0; j < 8; ++j) ph[j] = (_Float16)(a[j] * rd);
        *reinterpret_cast<half8*>(p_new + off) = ph;
    }
}

extern "C" void kernel_launch(void* const* d_in, const int* in_sizes, int n_in,
                              void* d_out, int out_size, void* d_ws, size_t ws_size,
                              hipStream_t stream) {
    const int*   edge_index = (const int*)d_in[0];      // [2, E]: row then col
    const float* edge_attr  = (const float*)d_in[1];    // [E]
    const int*   target     = (const int*)d_in[2];      // [N]
    const float* weight     = (const float*)d_in[3];    // [C, S]
    float* out = (float*)d_out;                         // [N, C]

    const int* row = edge_index;
    const int* col = edge_index + NE;

    // ws layout (dwords):
    //   rdeg[PADN] | bcur[1024] | cnt[PADN] | tq[NN] int2 | edges[NN*PAD] | bin[NBUCK*CAP] uint2
    // aliases (sequential lifetimes): rbin = edges region (bin writes, degrdeg reads,
    // then place overwrites); pA|pB = tail 9.6 MB of bin (dead after place).
    float*        rdeg  = (float*)d_ws;
    int*          bcur  = (int*)(rdeg + PADN);
    int*          cnt   = bcur + 1024;
    int2*         tq    = (int2*)(cnt + PADN);
    unsigned int* edges = (unsigned int*)(tq + NN);
    unsigned int* rbin  = edges;
    uint2*        bin   = (uint2*)(edges + (size_t)NN * PAD);
    _Float16*     pA    = (_Float16*)((char*)bin + (size_t)NBUCK * CAP * sizeof(uint2)
                                      - (size_t)2 * NN * NC * sizeof(_Float16));
    _Float16*     pB    = pA + (size_t)NN * NC;

    hipMemsetAsync(bcur, 0, 1024 * sizeof(int), stream);  // bucket cursors only

    bin_kernel<<<(NE + EPB - 1) / EPB, 1024, 0, stream>>>(row, col, edge_attr,
            bcur, bin, rbin);
    degrdeg_kernel<<<NBUCK, 1024, 0, stream>>>(bcur, rbin, target, rdeg, tq);
    place_kernel<<<NBUCK, 1024, 0, stream>>>(bcur, bin, edges, cnt);

    const int gblocks = (NN * 6 + 255) / 256;
    _Float16* p = pA;
    _Float16* p_new = pB;
    step1_kernel<<<gblocks, 256, 0, stream>>>(cnt, edges, tq, rdeg, weight, p, out);
    for (int t = 2; t <= NS - 1; ++t) {
        gather_kernel<false><<<gblocks, 256, 0, stream>>>(cnt, edges, rdeg, p, p_new,
                                                          weight, t, out);
        _Float16* tmp = p; p = p_new; p_new = tmp;
    }
    gather_kernel<true><<<gblocks, 256, 0, stream>>>(cnt, edges, rdeg, p, p_new,
                                                     weight, NS, out);
}